// Round 14
// baseline (829.116 us; speedup 1.0000x reference)
//
#include <hip/hip_runtime.h>
#include <hip/hip_fp16.h>
#include <math.h>

constexpr int N_NODES = 100000;
constexpr int N_EDGES = 1600000;
constexpr int H       = 128;   // HIDDEN == NUM_FILTERS
constexpr int NG      = 50;    // NUM_GAUSSIANS
constexpr int EPT     = 32;    // edges per tile
constexpr int NT      = N_EDGES / EPT;  // 50000 tiles
constexpr int EBLK    = 2560;  // edge-kernel grid
constexpr int NBINS   = 98 * 1024;     // 100352 >= N_NODES
constexpr int NODEB   = N_NODES / 32;  // 3125 node-tile blocks

typedef _Float16 f16x8 __attribute__((ext_vector_type(8)));
typedef _Float16 f16x2 __attribute__((ext_vector_type(2)));
typedef float    f32x4 __attribute__((ext_vector_type(4)));

__device__ __forceinline__ float ssp_fast(float v) {
    return fmaxf(v, 0.0f) + __logf(1.0f + __expf(-fabsf(v))) - 0.69314718056f;
}

// Stage a 32-row x 128-col f32 tile into XOR-swizzled fp16 LDS.
__device__ __forceinline__ void stage_tile_fp16(
    const float* __restrict__ src, _Float16* lds, int tid)
{
    const int row = tid >> 3;
    const int c0  = (tid & 7) * 16;
    const float* s = src + row * H + c0;
    #pragma unroll
    for (int half = 0; half < 2; ++half) {
        float4 f0 = *reinterpret_cast<const float4*>(s + half * 8);
        float4 f1 = *reinterpret_cast<const float4*>(s + half * 8 + 4);
        f16x8 v;
        v[0] = (_Float16)f0.x; v[1] = (_Float16)f0.y;
        v[2] = (_Float16)f0.z; v[3] = (_Float16)f0.w;
        v[4] = (_Float16)f1.x; v[5] = (_Float16)f1.y;
        v[6] = (_Float16)f1.z; v[7] = (_Float16)f1.w;
        unsigned off = (unsigned)(row * H + c0 + half * 8) * 2u;
        off ^= (unsigned)((row & 7) << 4);
        *reinterpret_cast<f16x8*>(reinterpret_cast<char*>(lds) + off) = v;
    }
}

// ===== prep0: zero agg + lin1 (fp16 MFMA, paired output) + edge histogram =====
__global__ __launch_bounds__(256) void prep0_kernel(
    const int* __restrict__ ei, const float* __restrict__ h,
    const float* __restrict__ w, __half2* __restrict__ xp,
    int* __restrict__ bins, float* __restrict__ agg)
{
    __shared__ alignas(16) _Float16 a_lds[32 * H];

    const int tid  = threadIdx.x;
    const int gtid = blockIdx.x * 256 + tid;
    const int gsz  = NODEB * 256;

    // zero agg
    {
        float4 z = {0.0f, 0.0f, 0.0f, 0.0f};
        float4* agg4 = reinterpret_cast<float4*>(agg);
        for (int i = gtid; i < N_NODES * H / 4; i += gsz) agg4[i] = z;
    }

    const int wv  = tid >> 6;
    const int l   = tid & 63;
    const int lhi = l >> 4;
    const int llo = l & 15;

    f16x8 bf[2][4];
    #pragma unroll
    for (int nf = 0; nf < 2; ++nf) {
        const int n = wv * 32 + nf * 16 + llo;
        #pragma unroll
        for (int ks = 0; ks < 4; ++ks)
            #pragma unroll
            for (int i = 0; i < 8; ++i)
                bf[nf][ks][i] = (_Float16)w[(ks * 32 + lhi * 8 + i) * H + n];
    }

    stage_tile_fp16(h + (size_t)blockIdx.x * 32 * H, a_lds, tid);
    __syncthreads();

    const f32x4 zero4 = {0.0f, 0.0f, 0.0f, 0.0f};
    f32x4 c[2][2];
    #pragma unroll
    for (int m = 0; m < 2; ++m)
        #pragma unroll
        for (int nf = 0; nf < 2; ++nf) c[m][nf] = zero4;

    #pragma unroll
    for (int msub = 0; msub < 2; ++msub) {
        const int rowa = msub * 16 + llo;
        #pragma unroll
        for (int ks = 0; ks < 4; ++ks) {
            unsigned off = (unsigned)(rowa * H) * 2u + (unsigned)(ks * 64 + lhi * 16);
            off ^= (unsigned)((rowa & 7) << 4);
            const f16x8 a = *reinterpret_cast<const f16x8*>(
                reinterpret_cast<const char*>(a_lds) + off);
            #pragma unroll
            for (int nf = 0; nf < 2; ++nf)
                c[msub][nf] = __builtin_amdgcn_mfma_f32_16x16x32_f16(
                    a, bf[nf][ks], c[msub][nf], 0, 0, 0);
        }
    }

    // store paired: xp[node*64 + wv*16 + llo] = (x[wv*32+llo], x[wv*32+16+llo])
    #pragma unroll
    for (int msub = 0; msub < 2; ++msub)
        #pragma unroll
        for (int j = 0; j < 4; ++j) {
            const int node = blockIdx.x * 32 + msub * 16 + lhi * 4 + j;
            xp[(size_t)node * 64 + wv * 16 + llo] =
                __floats2half2_rn(c[msub][0][j], c[msub][1][j]);
        }

    // edge histogram (bins pre-zeroed by memset)
    for (int e = gtid; e < N_EDGES; e += gsz)
        atomicAdd(&bins[ei[e]], 1);
}

// ================= counting sort of edges by row =================
__global__ __launch_bounds__(1024) void scanA_kernel(
    int* __restrict__ bins, int* __restrict__ bsum)
{
    __shared__ int ts[1024];
    const int i = blockIdx.x * 1024 + threadIdx.x;
    const int v = bins[i];
    ts[threadIdx.x] = v;
    __syncthreads();
    for (int d = 1; d < 1024; d <<= 1) {
        int t = (threadIdx.x >= d) ? ts[threadIdx.x - d] : 0;
        __syncthreads();
        ts[threadIdx.x] += t;
        __syncthreads();
    }
    bins[i] = ts[threadIdx.x] - v;           // exclusive within chunk
    if (threadIdx.x == 1023) bsum[blockIdx.x] = ts[1023];  // chunk total
}

// scatter: local top-scan of 98 chunk totals + permute + precompute d, cc
__global__ __launch_bounds__(256) void scatter_kernel(
    const int* __restrict__ ei, const float* __restrict__ pos,
    int* __restrict__ bins, const int* __restrict__ bsum,
    int4* __restrict__ meta)
{
    __shared__ int pre[128];
    const int tid = threadIdx.x;
    int myv = 0;
    if (tid < 128) {
        myv = (tid < 98) ? bsum[tid] : 0;
        pre[tid] = myv;
    }
    __syncthreads();
    for (int d = 1; d < 128; d <<= 1) {
        int t = (tid < 128 && tid >= d) ? pre[tid - d] : 0;
        __syncthreads();
        if (tid < 128) pre[tid] += t;
        __syncthreads();
    }
    if (tid < 128) pre[tid] -= myv;   // exclusive prefix of chunk totals
    __syncthreads();

    const int e = blockIdx.x * 256 + tid;
    if (e < N_EDGES) {
        const int r = ei[e];
        const int c = ei[N_EDGES + e];
        const int p = atomicAdd(&bins[r], 1) + pre[r >> 10];
        const float dx = pos[3 * r + 0] - pos[3 * c + 0];
        const float dy = pos[3 * r + 1] - pos[3 * c + 1];
        const float dz = pos[3 * r + 2] - pos[3 * c + 2];
        const float d  = sqrtf(dx * dx + dy * dy + dz * dz);
        const float cc = 0.5f * cosf(d * 0.31415926535897931f) + 0.5f;
        meta[p] = make_int4(r, __float_as_int(cc), c, __float_as_int(d));
    }
}

// ========== edge kernel: r11 structure exactly, paired-x gather ==========
__global__ __launch_bounds__(256, 4) void edge_kernel(
    const int4* __restrict__ meta, const __half2* __restrict__ xp,
    const float* __restrict__ w1, const float* __restrict__ b1,
    const float* __restrict__ w2, const float* __restrict__ b2,
    float* __restrict__ agg)
{
    __shared__ alignas(16) _Float16 t_lds[EPT * H];      // 8 KB, XOR-swizzled
    __shared__ alignas(16) _Float16 attr_lds[EPT * 64];  // 4 KB, XOR-swizzled

    const int tid = threadIdx.x;
    const int w   = tid >> 6;
    const int l   = tid & 63;
    const int lhi = l >> 4;
    const int llo = l & 15;

    constexpr float GSTEP = 10.0f / 49.0f;
    constexpr float GINV  = 4.9f;                 // 1/GSTEP
    constexpr float GCOEF = -12.005f;

    f16x8 b1f[2][2];
    #pragma unroll
    for (int nf = 0; nf < 2; ++nf) {
        const int n = w * 32 + nf * 16 + llo;
        #pragma unroll
        for (int ks = 0; ks < 2; ++ks) {
            #pragma unroll
            for (int i = 0; i < 8; ++i) {
                const int k = ks * 32 + lhi * 8 + i;
                b1f[nf][ks][i] = (k < NG) ? (_Float16)w1[k * H + n] : (_Float16)0.0f;
            }
        }
    }
    f16x8 b2f[2][4];
    #pragma unroll
    for (int nf = 0; nf < 2; ++nf) {
        const int n = w * 32 + nf * 16 + llo;
        #pragma unroll
        for (int ks = 0; ks < 4; ++ks) {
            #pragma unroll
            for (int i = 0; i < 8; ++i) {
                const int k = ks * 32 + lhi * 8 + i;
                b2f[nf][ks][i] = (_Float16)w2[k * H + n];
            }
        }
    }
    const float b1v[2] = { b1[w * 32 + llo], b1[w * 32 + 16 + llo] };
    const float b2v[2] = { b2[w * 32 + llo], b2[w * 32 + 16 + llo] };

    const f32x4 zero4 = {0.0f, 0.0f, 0.0f, 0.0f};
    const f16x8 zf16  = {(_Float16)0, (_Float16)0, (_Float16)0, (_Float16)0,
                         (_Float16)0, (_Float16)0, (_Float16)0, (_Float16)0};

    for (int t = blockIdx.x; t < NT; t += gridDim.x) {
        const int4* mt = meta + (size_t)t * EPT;

        // ---- R0: zero attr tile (prev stage1 done with it per bar2) ----
        *reinterpret_cast<f16x8*>(
            reinterpret_cast<char*>(attr_lds) + tid * 16) = zf16;
        __syncthreads();  // barA

        // ---- R1: windowed Gaussian, 2 exps/thread (8 threads per edge) ----
        {
            const int ae = tid >> 3;       // edge 0..31
            const int p  = tid & 7;
            const float d = __int_as_float(
                reinterpret_cast<const int*>(mt + ae)[3]);
            int g0 = (int)(d * GINV + 0.5f) - 7;
            g0 &= ~1;
            g0 = max(0, min(48, g0));
            const int g = g0 + 2 * p;
            const float df0 = d - (float)g * GSTEP;
            const float df1 = d - (float)(g + 1) * GSTEP;
            f16x2 v;
            v[0] = (_Float16)__expf(GCOEF * df0 * df0);
            v[1] = (_Float16)__expf(GCOEF * df1 * df1);
            unsigned off = (unsigned)(ae * 128 + g * 2);
            off ^= (unsigned)((ae & 7) << 4);
            *reinterpret_cast<f16x2*>(
                reinterpret_cast<char*>(attr_lds) + off) = v;
        }
        __syncthreads();  // bar1: attr visible; prev stage2 done with t_lds

        // ---- x-gather: one half2 per edge (pairs f and f+16), drains at bar2 ----
        float xv[2][4][2];
        #pragma unroll
        for (int msub = 0; msub < 2; ++msub)
            #pragma unroll
            for (int j = 0; j < 4; ++j) {
                const int edge = msub * 16 + lhi * 4 + j;
                const int col  = reinterpret_cast<const int*>(mt + edge)[2];
                const float2 fv = __half22float2(xp[col * 64 + w * 16 + llo]);
                xv[msub][j][0] = fv.x;
                xv[msub][j][1] = fv.y;
            }

        // ---- stage 1: c1 = attr @ w1 ----
        f32x4 c1[2][2];
        #pragma unroll
        for (int m = 0; m < 2; ++m)
            #pragma unroll
            for (int nf = 0; nf < 2; ++nf) c1[m][nf] = zero4;

        #pragma unroll
        for (int msub = 0; msub < 2; ++msub) {
            const int ea = msub * 16 + llo;
            #pragma unroll
            for (int ks = 0; ks < 2; ++ks) {
                unsigned off = (unsigned)(ea * 128 + ks * 64 + lhi * 16);
                off ^= (unsigned)((ea & 7) << 4);
                const f16x8 a1 = *reinterpret_cast<const f16x8*>(
                    reinterpret_cast<const char*>(attr_lds) + off);
                #pragma unroll
                for (int nf = 0; nf < 2; ++nf)
                    c1[msub][nf] = __builtin_amdgcn_mfma_f32_16x16x32_f16(
                        a1, b1f[nf][ks], c1[msub][nf], 0, 0, 0);
            }
        }

        // ---- bias + ssp -> t_lds ----
        #pragma unroll
        for (int msub = 0; msub < 2; ++msub)
            #pragma unroll
            for (int nf = 0; nf < 2; ++nf)
                #pragma unroll
                for (int j = 0; j < 4; ++j) {
                    const int edge = msub * 16 + lhi * 4 + j;
                    const int filt = w * 32 + nf * 16 + llo;
                    const float tv = ssp_fast(c1[msub][nf][j] + b1v[nf]);
                    unsigned off = (unsigned)(edge * H + filt) * 2u;
                    off ^= (unsigned)((edge & 7) << 4);
                    *reinterpret_cast<_Float16*>(
                        reinterpret_cast<char*>(t_lds) + off) = (_Float16)tv;
                }

        __syncthreads();  // bar2: t_lds visible; xv drained

        // ---- epilogue meta loads (cover under stage 2) ----
        int2 rcA[2][4];
        #pragma unroll
        for (int msub = 0; msub < 2; ++msub)
            #pragma unroll
            for (int j = 0; j < 4; ++j)
                rcA[msub][j] = *reinterpret_cast<const int2*>(
                    mt + msub * 16 + lhi * 4 + j);

        // ---- stage 2: c2 = t @ w2 ----
        f32x4 c2[2][2];
        #pragma unroll
        for (int m = 0; m < 2; ++m)
            #pragma unroll
            for (int nf = 0; nf < 2; ++nf) c2[m][nf] = zero4;

        #pragma unroll
        for (int ks = 0; ks < 4; ++ks) {
            f16x8 a2[2];
            #pragma unroll
            for (int msub = 0; msub < 2; ++msub) {
                const int edge = msub * 16 + llo;
                unsigned off = (unsigned)(edge * H) * 2u
                             + (unsigned)(ks * 64 + lhi * 16);
                off ^= (unsigned)((edge & 7) << 4);
                a2[msub] = *reinterpret_cast<const f16x8*>(
                    reinterpret_cast<const char*>(t_lds) + off);
            }
            #pragma unroll
            for (int msub = 0; msub < 2; ++msub)
                #pragma unroll
                for (int nf = 0; nf < 2; ++nf)
                    c2[msub][nf] = __builtin_amdgcn_mfma_f32_16x16x32_f16(
                        a2[msub], b2f[nf][ks], c2[msub][nf], 0, 0, 0);
        }

        // ---- epilogue: segmented reduce over sorted rows, then few atomics ----
        #pragma unroll
        for (int msub = 0; msub < 2; ++msub) {
            int rr[4]; float cce[4];
            #pragma unroll
            for (int j = 0; j < 4; ++j) {
                rr[j]  = rcA[msub][j].x;
                cce[j] = __int_as_float(rcA[msub][j].y);
            }
            const bool bB1 = rr[1] != rr[0];
            const bool bB2 = rr[2] != rr[1];
            const bool bB3 = rr[3] != rr[2];
            const bool closed = bB1 | bB2 | bB3;
            const int  prev_t = __shfl_up(rr[3], 16);
            const int  next_h = __shfl_down(rr[0], 16);
            const bool mrg  = (lhi > 0) && (rr[0] == prev_t);
            const bool sing = !closed;
            const bool issue_tail = (lhi == 3) || (next_h != rr[3]);

            float v0[4], v1[4];
            #pragma unroll
            for (int j = 0; j < 4; ++j) {
                v0[j] = (c2[msub][0][j] + b2v[0]) * cce[j] * xv[msub][j][0];
                v1[j] = (c2[msub][1][j] + b2v[1]) * cce[j] * xv[msub][j][1];
            }
            const int fc0 = w * 32 + llo;
            const int fc1 = fc0 + 16;

            float h0 = v0[0], h1 = v1[0];
            if (!bB1) { h0 += v0[1]; h1 += v1[1];
                if (!bB2) { h0 += v0[2]; h1 += v1[2];
                    if (!bB3) { h0 += v0[3]; h1 += v1[3]; } } }
            float cs0 = v0[3], cs1 = v1[3];
            if (!bB3) { cs0 += v0[2]; cs1 += v1[2];
                if (!bB2) { cs0 += v0[1]; cs1 += v1[1];
                    if (!bB1) { cs0 += v0[0]; cs1 += v1[0]; } } }

            if (bB1 && bB2) { atomicAdd(&agg[rr[1] * H + fc0], v0[1]);
                              atomicAdd(&agg[rr[1] * H + fc1], v1[1]); }
            if (bB2 && bB3) { atomicAdd(&agg[rr[2] * H + fc0], v0[2]);
                              atomicAdd(&agg[rr[2] * H + fc1], v1[2]); }
            if (bB1 && !bB2 && bB3) {
                atomicAdd(&agg[rr[1] * H + fc0], v0[1] + v0[2]);
                atomicAdd(&agg[rr[1] * H + fc1], v1[1] + v1[2]);
            }

            bool f = !(sing && mrg);
            {
                float p0 = __shfl_up(cs0, 16), p1 = __shfl_up(cs1, 16);
                int   pf = __shfl_up((int)f, 16);
                if (lhi >= 1 && !f) { cs0 += p0; cs1 += p1; f = (bool)pf; }
            }
            {
                float p0 = __shfl_up(cs0, 32), p1 = __shfl_up(cs1, 32);
                int   pf = __shfl_up((int)f, 32);
                if (lhi >= 2 && !f) { cs0 += p0; cs1 += p1; f = (bool)pf; }
            }
            const float car0 = __shfl_up(cs0, 16);
            const float car1 = __shfl_up(cs1, 16);

            if (closed) {
                atomicAdd(&agg[rr[0] * H + fc0], h0 + (mrg ? car0 : 0.0f));
                atomicAdd(&agg[rr[0] * H + fc1], h1 + (mrg ? car1 : 0.0f));
            }
            if (issue_tail) {
                atomicAdd(&agg[rr[3] * H + fc0], cs0);
                atomicAdd(&agg[rr[3] * H + fc1], cs1);
            }
        }
    }
}

// ===== final: out = ssp(agg @ lin2_w + lin2_b) @ lin_w + lin_b (fp16 MFMA) =====
__global__ __launch_bounds__(256) void final_kernel(
    const float* __restrict__ agg,
    const float* __restrict__ w2l, const float* __restrict__ b2l,
    const float* __restrict__ wl,  const float* __restrict__ bl,
    float* __restrict__ out)
{
    __shared__ alignas(16) _Float16 a_lds[32 * H];
    __shared__ alignas(16) _Float16 t_lds[32 * H];

    const int tid = threadIdx.x;
    const int wv  = tid >> 6;
    const int l   = tid & 63;
    const int lhi = l >> 4;
    const int llo = l & 15;

    f16x8 b1f[2][4], b2f[2][4];
    #pragma unroll
    for (int nf = 0; nf < 2; ++nf) {
        const int n = wv * 32 + nf * 16 + llo;
        #pragma unroll
        for (int ks = 0; ks < 4; ++ks)
            #pragma unroll
            for (int i = 0; i < 8; ++i) {
                const int k = ks * 32 + lhi * 8 + i;
                b1f[nf][ks][i] = (_Float16)w2l[k * H + n];
                b2f[nf][ks][i] = (_Float16)wl[k * H + n];
            }
    }
    const float b2v[2] = { b2l[wv * 32 + llo], b2l[wv * 32 + 16 + llo] };
    const float bv[2]  = { bl[wv * 32 + llo],  bl[wv * 32 + 16 + llo]  };

    stage_tile_fp16(agg + (size_t)blockIdx.x * 32 * H, a_lds, tid);
    __syncthreads();

    f32x4 c1[2][2];
    #pragma unroll
    for (int m = 0; m < 2; ++m)
        #pragma unroll
        for (int nf = 0; nf < 2; ++nf) {
            c1[m][nf][0] = b2v[nf]; c1[m][nf][1] = b2v[nf];
            c1[m][nf][2] = b2v[nf]; c1[m][nf][3] = b2v[nf];
        }

    #pragma unroll
    for (int msub = 0; msub < 2; ++msub) {
        const int rowa = msub * 16 + llo;
        #pragma unroll
        for (int ks = 0; ks < 4; ++ks) {
            unsigned off = (unsigned)(rowa * H) * 2u + (unsigned)(ks * 64 + lhi * 16);
            off ^= (unsigned)((rowa & 7) << 4);
            const f16x8 a = *reinterpret_cast<const f16x8*>(
                reinterpret_cast<const char*>(a_lds) + off);
            #pragma unroll
            for (int nf = 0; nf < 2; ++nf)
                c1[msub][nf] = __builtin_amdgcn_mfma_f32_16x16x32_f16(
                    a, b1f[nf][ks], c1[msub][nf], 0, 0, 0);
        }
    }

    #pragma unroll
    for (int msub = 0; msub < 2; ++msub)
        #pragma unroll
        for (int nf = 0; nf < 2; ++nf)
            #pragma unroll
            for (int j = 0; j < 4; ++j) {
                const int rowc = msub * 16 + lhi * 4 + j;
                const int filt = wv * 32 + nf * 16 + llo;
                const float tv = ssp_fast(c1[msub][nf][j]);
                unsigned off = (unsigned)(rowc * H + filt) * 2u;
                off ^= (unsigned)((rowc & 7) << 4);
                *reinterpret_cast<_Float16*>(
                    reinterpret_cast<char*>(t_lds) + off) = (_Float16)tv;
            }

    __syncthreads();

    f32x4 c2[2][2];
    #pragma unroll
    for (int m = 0; m < 2; ++m)
        #pragma unroll
        for (int nf = 0; nf < 2; ++nf) {
            c2[m][nf][0] = bv[nf]; c2[m][nf][1] = bv[nf];
            c2[m][nf][2] = bv[nf]; c2[m][nf][3] = bv[nf];
        }

    #pragma unroll
    for (int msub = 0; msub < 2; ++msub) {
        const int rowa = msub * 16 + llo;
        #pragma unroll
        for (int ks = 0; ks < 4; ++ks) {
            unsigned off = (unsigned)(rowa * H) * 2u + (unsigned)(ks * 64 + lhi * 16);
            off ^= (unsigned)((rowa & 7) << 4);
            const f16x8 a = *reinterpret_cast<const f16x8*>(
                reinterpret_cast<const char*>(t_lds) + off);
            #pragma unroll
            for (int nf = 0; nf < 2; ++nf)
                c2[msub][nf] = __builtin_amdgcn_mfma_f32_16x16x32_f16(
                    a, b2f[nf][ks], c2[msub][nf], 0, 0, 0);
        }
    }

    #pragma unroll
    for (int msub = 0; msub < 2; ++msub)
        #pragma unroll
        for (int nf = 0; nf < 2; ++nf)
            #pragma unroll
            for (int j = 0; j < 4; ++j) {
                const int node = blockIdx.x * 32 + msub * 16 + lhi * 4 + j;
                const int filt = wv * 32 + nf * 16 + llo;
                out[(size_t)node * H + filt] = c2[msub][nf][j];
            }
}

extern "C" void kernel_launch(void* const* d_in, const int* in_sizes, int n_in,
                              void* d_out, int out_size, void* d_ws, size_t ws_size,
                              hipStream_t stream) {
    const float* h      = (const float*)d_in[0];
    const float* pos    = (const float*)d_in[1];
    const int*   ei     = (const int*)  d_in[2];
    const float* mlp_w1 = (const float*)d_in[3];
    const float* mlp_b1 = (const float*)d_in[4];
    const float* mlp_w2 = (const float*)d_in[5];
    const float* mlp_b2 = (const float*)d_in[6];
    const float* lin1_w = (const float*)d_in[7];
    const float* lin2_w = (const float*)d_in[8];
    const float* lin2_b = (const float*)d_in[9];
    const float* lin_w  = (const float*)d_in[10];
    const float* lin_b  = (const float*)d_in[11];

    float* out = (float*)d_out;
    char*  ws  = (char*)d_ws;
    float* agg  = (float*)ws;                               // 51.2 MB
    char*  p    = ws + (size_t)N_NODES * H * 4;
    int*   bins = (int*)p;                                  // 401 KB
    int*   bsum = (int*)(p + (size_t)NBINS * 4);            // 98 ints

    // d_out doubles as scratch until final_kernel overwrites it:
    __half2* xp  = (__half2*)d_out;                         // 25.6 MB paired lin1 out
    int4*   meta = (int4*)((char*)d_out + (size_t)N_NODES * 64 * 4);  // 25.6 MB

    hipMemsetAsync(bins, 0, (size_t)NBINS * sizeof(int), stream);
    prep0_kernel<<<NODEB, 256, 0, stream>>>(ei, h, lin1_w, xp, bins, agg);
    scanA_kernel<<<NBINS / 1024, 1024, 0, stream>>>(bins, bsum);
    scatter_kernel<<<(N_EDGES + 255) / 256, 256, 0, stream>>>(ei, pos, bins,
                                                              bsum, meta);
    edge_kernel<<<EBLK, 256, 0, stream>>>(meta, xp, mlp_w1, mlp_b1,
                                          mlp_w2, mlp_b2, agg);
    final_kernel<<<NODEB, 256, 0, stream>>>(agg, lin2_w, lin2_b,
                                            lin_w, lin_b, out);
}

// Round 15
// 485.411 us; speedup vs baseline: 1.7081x; 1.7081x over previous
//
#include <hip/hip_runtime.h>
#include <hip/hip_fp16.h>
#include <math.h>

constexpr int N_NODES = 100000;
constexpr int N_EDGES = 1600000;
constexpr int H       = 128;   // HIDDEN == NUM_FILTERS
constexpr int NG      = 50;    // NUM_GAUSSIANS
constexpr int EPT     = 32;    // edges per tile
constexpr int NT      = N_EDGES / EPT;  // 50000 tiles
constexpr int EBLK    = 2560;  // edge-kernel grid
constexpr int NBINS   = 98 * 1024;     // 100352 >= N_NODES
constexpr int NODEB   = N_NODES / 32;  // 3125 node-tile blocks

typedef _Float16 f16x8 __attribute__((ext_vector_type(8)));
typedef _Float16 f16x2 __attribute__((ext_vector_type(2)));
typedef float    f32x4 __attribute__((ext_vector_type(4)));

__device__ __forceinline__ float ssp_fast(float v) {
    return fmaxf(v, 0.0f) + __logf(1.0f + __expf(-fabsf(v))) - 0.69314718056f;
}

// Stage a 32-row x 128-col f32 tile into XOR-swizzled fp16 LDS.
__device__ __forceinline__ void stage_tile_fp16(
    const float* __restrict__ src, _Float16* lds, int tid)
{
    const int row = tid >> 3;
    const int c0  = (tid & 7) * 16;
    const float* s = src + row * H + c0;
    #pragma unroll
    for (int half = 0; half < 2; ++half) {
        float4 f0 = *reinterpret_cast<const float4*>(s + half * 8);
        float4 f1 = *reinterpret_cast<const float4*>(s + half * 8 + 4);
        f16x8 v;
        v[0] = (_Float16)f0.x; v[1] = (_Float16)f0.y;
        v[2] = (_Float16)f0.z; v[3] = (_Float16)f0.w;
        v[4] = (_Float16)f1.x; v[5] = (_Float16)f1.y;
        v[6] = (_Float16)f1.z; v[7] = (_Float16)f1.w;
        unsigned off = (unsigned)(row * H + c0 + half * 8) * 2u;
        off ^= (unsigned)((row & 7) << 4);
        *reinterpret_cast<f16x8*>(reinterpret_cast<char*>(lds) + off) = v;
    }
}

// ===== prep0: zero agg + lin1 (fp16 MFMA) + edge histogram =====
__global__ __launch_bounds__(256) void prep0_kernel(
    const int* __restrict__ ei, const float* __restrict__ h,
    const float* __restrict__ w, __half* __restrict__ x,
    int* __restrict__ bins, float* __restrict__ agg)
{
    __shared__ alignas(16) _Float16 a_lds[32 * H];

    const int tid  = threadIdx.x;
    const int gtid = blockIdx.x * 256 + tid;
    const int gsz  = NODEB * 256;

    // zero agg
    {
        float4 z = {0.0f, 0.0f, 0.0f, 0.0f};
        float4* agg4 = reinterpret_cast<float4*>(agg);
        for (int i = gtid; i < N_NODES * H / 4; i += gsz) agg4[i] = z;
    }

    const int wv  = tid >> 6;
    const int l   = tid & 63;
    const int lhi = l >> 4;
    const int llo = l & 15;

    f16x8 bf[2][4];
    #pragma unroll
    for (int nf = 0; nf < 2; ++nf) {
        const int n = wv * 32 + nf * 16 + llo;
        #pragma unroll
        for (int ks = 0; ks < 4; ++ks)
            #pragma unroll
            for (int i = 0; i < 8; ++i)
                bf[nf][ks][i] = (_Float16)w[(ks * 32 + lhi * 8 + i) * H + n];
    }

    stage_tile_fp16(h + (size_t)blockIdx.x * 32 * H, a_lds, tid);
    __syncthreads();

    const f32x4 zero4 = {0.0f, 0.0f, 0.0f, 0.0f};
    f32x4 c[2][2];
    #pragma unroll
    for (int m = 0; m < 2; ++m)
        #pragma unroll
        for (int nf = 0; nf < 2; ++nf) c[m][nf] = zero4;

    #pragma unroll
    for (int msub = 0; msub < 2; ++msub) {
        const int rowa = msub * 16 + llo;
        #pragma unroll
        for (int ks = 0; ks < 4; ++ks) {
            unsigned off = (unsigned)(rowa * H) * 2u + (unsigned)(ks * 64 + lhi * 16);
            off ^= (unsigned)((rowa & 7) << 4);
            const f16x8 a = *reinterpret_cast<const f16x8*>(
                reinterpret_cast<const char*>(a_lds) + off);
            #pragma unroll
            for (int nf = 0; nf < 2; ++nf)
                c[msub][nf] = __builtin_amdgcn_mfma_f32_16x16x32_f16(
                    a, bf[nf][ks], c[msub][nf], 0, 0, 0);
        }
    }

    #pragma unroll
    for (int msub = 0; msub < 2; ++msub)
        #pragma unroll
        for (int nf = 0; nf < 2; ++nf)
            #pragma unroll
            for (int j = 0; j < 4; ++j) {
                const int node = blockIdx.x * 32 + msub * 16 + lhi * 4 + j;
                const int filt = wv * 32 + nf * 16 + llo;
                x[(size_t)node * H + filt] = __float2half(c[msub][nf][j]);
            }

    // edge histogram (bins pre-zeroed by memset)
    for (int e = gtid; e < N_EDGES; e += gsz)
        atomicAdd(&bins[ei[e]], 1);
}

// ================= counting sort of edges by row =================
__global__ __launch_bounds__(1024) void scanA_kernel(
    int* __restrict__ bins, int* __restrict__ bsum)
{
    __shared__ int ts[1024];
    const int i = blockIdx.x * 1024 + threadIdx.x;
    const int v = bins[i];
    ts[threadIdx.x] = v;
    __syncthreads();
    for (int d = 1; d < 1024; d <<= 1) {
        int t = (threadIdx.x >= d) ? ts[threadIdx.x - d] : 0;
        __syncthreads();
        ts[threadIdx.x] += t;
        __syncthreads();
    }
    bins[i] = ts[threadIdx.x] - v;           // exclusive within chunk
    if (threadIdx.x == 1023) bsum[blockIdx.x] = ts[1023];  // chunk total
}

// scatter: local top-scan of 98 chunk totals + permute + precompute d, cc
__global__ __launch_bounds__(256) void scatter_kernel(
    const int* __restrict__ ei, const float* __restrict__ pos,
    int* __restrict__ bins, const int* __restrict__ bsum,
    int4* __restrict__ meta)
{
    __shared__ int pre[128];
    const int tid = threadIdx.x;
    int myv = 0;
    if (tid < 128) {
        myv = (tid < 98) ? bsum[tid] : 0;
        pre[tid] = myv;
    }
    __syncthreads();
    for (int d = 1; d < 128; d <<= 1) {
        int t = (tid < 128 && tid >= d) ? pre[tid - d] : 0;
        __syncthreads();
        if (tid < 128) pre[tid] += t;
        __syncthreads();
    }
    if (tid < 128) pre[tid] -= myv;   // exclusive prefix of chunk totals
    __syncthreads();

    const int e = blockIdx.x * 256 + tid;
    if (e < N_EDGES) {
        const int r = ei[e];
        const int c = ei[N_EDGES + e];
        const int p = atomicAdd(&bins[r], 1) + pre[r >> 10];
        const float dx = pos[3 * r + 0] - pos[3 * c + 0];
        const float dy = pos[3 * r + 1] - pos[3 * c + 1];
        const float dz = pos[3 * r + 2] - pos[3 * c + 2];
        const float d  = sqrtf(dx * dx + dy * dy + dz * dz);
        const float cc = 0.5f * cosf(d * 0.31415926535897931f) + 0.5f;
        meta[p] = make_int4(r, __float_as_int(cc), c, __float_as_int(d));
    }
}

// ========== edge kernel: exact round-11 structure (311 us measured) ==========
__global__ __launch_bounds__(256) void edge_kernel(
    const int4* __restrict__ meta, const __half* __restrict__ x,
    const float* __restrict__ w1, const float* __restrict__ b1,
    const float* __restrict__ w2, const float* __restrict__ b2,
    float* __restrict__ agg)
{
    __shared__ alignas(16) _Float16 t_lds[EPT * H];      // 8 KB, XOR-swizzled
    __shared__ alignas(16) _Float16 attr_lds[EPT * 64];  // 4 KB, XOR-swizzled

    const int tid = threadIdx.x;
    const int w   = tid >> 6;
    const int l   = tid & 63;
    const int lhi = l >> 4;
    const int llo = l & 15;

    constexpr float GSTEP = 10.0f / 49.0f;
    constexpr float GINV  = 4.9f;                 // 1/GSTEP
    constexpr float GCOEF = -12.005f;

    f16x8 b1f[2][2];
    #pragma unroll
    for (int nf = 0; nf < 2; ++nf) {
        const int n = w * 32 + nf * 16 + llo;
        #pragma unroll
        for (int ks = 0; ks < 2; ++ks) {
            #pragma unroll
            for (int i = 0; i < 8; ++i) {
                const int k = ks * 32 + lhi * 8 + i;
                b1f[nf][ks][i] = (k < NG) ? (_Float16)w1[k * H + n] : (_Float16)0.0f;
            }
        }
    }
    f16x8 b2f[2][4];
    #pragma unroll
    for (int nf = 0; nf < 2; ++nf) {
        const int n = w * 32 + nf * 16 + llo;
        #pragma unroll
        for (int ks = 0; ks < 4; ++ks) {
            #pragma unroll
            for (int i = 0; i < 8; ++i) {
                const int k = ks * 32 + lhi * 8 + i;
                b2f[nf][ks][i] = (_Float16)w2[k * H + n];
            }
        }
    }
    const float b1v[2] = { b1[w * 32 + llo], b1[w * 32 + 16 + llo] };
    const float b2v[2] = { b2[w * 32 + llo], b2[w * 32 + 16 + llo] };

    const f32x4 zero4 = {0.0f, 0.0f, 0.0f, 0.0f};
    const f16x8 zf16  = {(_Float16)0, (_Float16)0, (_Float16)0, (_Float16)0,
                         (_Float16)0, (_Float16)0, (_Float16)0, (_Float16)0};

    for (int t = blockIdx.x; t < NT; t += gridDim.x) {
        const int4* mt = meta + (size_t)t * EPT;

        // ---- R0: zero attr tile (prev stage1 done with it per bar2) ----
        *reinterpret_cast<f16x8*>(
            reinterpret_cast<char*>(attr_lds) + tid * 16) = zf16;
        __syncthreads();  // barA

        // ---- R1: windowed Gaussian, 2 exps/thread (8 threads per edge) ----
        {
            const int ae = tid >> 3;       // edge 0..31
            const int p  = tid & 7;
            const float d = __int_as_float(
                reinterpret_cast<const int*>(mt + ae)[3]);
            int g0 = (int)(d * GINV + 0.5f) - 7;
            g0 &= ~1;
            g0 = max(0, min(48, g0));
            const int g = g0 + 2 * p;
            const float df0 = d - (float)g * GSTEP;
            const float df1 = d - (float)(g + 1) * GSTEP;
            f16x2 v;
            v[0] = (_Float16)__expf(GCOEF * df0 * df0);
            v[1] = (_Float16)__expf(GCOEF * df1 * df1);
            unsigned off = (unsigned)(ae * 128 + g * 2);
            off ^= (unsigned)((ae & 7) << 4);
            *reinterpret_cast<f16x2*>(
                reinterpret_cast<char*>(attr_lds) + off) = v;
        }
        __syncthreads();  // bar1: attr visible; prev stage2 done with t_lds

        // ---- x-gather: cols from meta, consumed in epilogue (drains at bar2) ----
        float xv[2][4][2];
        #pragma unroll
        for (int msub = 0; msub < 2; ++msub)
            #pragma unroll
            for (int j = 0; j < 4; ++j) {
                const int edge = msub * 16 + lhi * 4 + j;
                const int col  = reinterpret_cast<const int*>(mt + edge)[2];
                const int cbase = col * H + w * 32 + llo;
                xv[msub][j][0] = __half2float(x[cbase]);
                xv[msub][j][1] = __half2float(x[cbase + 16]);
            }

        // ---- stage 1: c1 = attr @ w1 ----
        f32x4 c1[2][2];
        #pragma unroll
        for (int m = 0; m < 2; ++m)
            #pragma unroll
            for (int nf = 0; nf < 2; ++nf) c1[m][nf] = zero4;

        #pragma unroll
        for (int msub = 0; msub < 2; ++msub) {
            const int ea = msub * 16 + llo;
            #pragma unroll
            for (int ks = 0; ks < 2; ++ks) {
                unsigned off = (unsigned)(ea * 128 + ks * 64 + lhi * 16);
                off ^= (unsigned)((ea & 7) << 4);
                const f16x8 a1 = *reinterpret_cast<const f16x8*>(
                    reinterpret_cast<const char*>(attr_lds) + off);
                #pragma unroll
                for (int nf = 0; nf < 2; ++nf)
                    c1[msub][nf] = __builtin_amdgcn_mfma_f32_16x16x32_f16(
                        a1, b1f[nf][ks], c1[msub][nf], 0, 0, 0);
            }
        }

        // ---- bias + ssp -> t_lds ----
        #pragma unroll
        for (int msub = 0; msub < 2; ++msub)
            #pragma unroll
            for (int nf = 0; nf < 2; ++nf)
                #pragma unroll
                for (int j = 0; j < 4; ++j) {
                    const int edge = msub * 16 + lhi * 4 + j;
                    const int filt = w * 32 + nf * 16 + llo;
                    const float tv = ssp_fast(c1[msub][nf][j] + b1v[nf]);
                    unsigned off = (unsigned)(edge * H + filt) * 2u;
                    off ^= (unsigned)((edge & 7) << 4);
                    *reinterpret_cast<_Float16*>(
                        reinterpret_cast<char*>(t_lds) + off) = (_Float16)tv;
                }

        __syncthreads();  // bar2: t_lds visible; xv drained

        // ---- epilogue meta loads (cover under stage 2) ----
        int2 rcA[2][4];
        #pragma unroll
        for (int msub = 0; msub < 2; ++msub)
            #pragma unroll
            for (int j = 0; j < 4; ++j)
                rcA[msub][j] = *reinterpret_cast<const int2*>(
                    mt + msub * 16 + lhi * 4 + j);

        // ---- stage 2: c2 = t @ w2 ----
        f32x4 c2[2][2];
        #pragma unroll
        for (int m = 0; m < 2; ++m)
            #pragma unroll
            for (int nf = 0; nf < 2; ++nf) c2[m][nf] = zero4;

        #pragma unroll
        for (int ks = 0; ks < 4; ++ks) {
            f16x8 a2[2];
            #pragma unroll
            for (int msub = 0; msub < 2; ++msub) {
                const int edge = msub * 16 + llo;
                unsigned off = (unsigned)(edge * H) * 2u
                             + (unsigned)(ks * 64 + lhi * 16);
                off ^= (unsigned)((edge & 7) << 4);
                a2[msub] = *reinterpret_cast<const f16x8*>(
                    reinterpret_cast<const char*>(t_lds) + off);
            }
            #pragma unroll
            for (int msub = 0; msub < 2; ++msub)
                #pragma unroll
                for (int nf = 0; nf < 2; ++nf)
                    c2[msub][nf] = __builtin_amdgcn_mfma_f32_16x16x32_f16(
                        a2[msub], b2f[nf][ks], c2[msub][nf], 0, 0, 0);
        }

        // ---- epilogue: segmented reduce over sorted rows, then few atomics ----
        #pragma unroll
        for (int msub = 0; msub < 2; ++msub) {
            int rr[4]; float cce[4];
            #pragma unroll
            for (int j = 0; j < 4; ++j) {
                rr[j]  = rcA[msub][j].x;
                cce[j] = __int_as_float(rcA[msub][j].y);
            }
            const bool bB1 = rr[1] != rr[0];
            const bool bB2 = rr[2] != rr[1];
            const bool bB3 = rr[3] != rr[2];
            const bool closed = bB1 | bB2 | bB3;
            const int  prev_t = __shfl_up(rr[3], 16);
            const int  next_h = __shfl_down(rr[0], 16);
            const bool mrg  = (lhi > 0) && (rr[0] == prev_t);
            const bool sing = !closed;
            const bool issue_tail = (lhi == 3) || (next_h != rr[3]);

            float v0[4], v1[4];
            #pragma unroll
            for (int j = 0; j < 4; ++j) {
                v0[j] = (c2[msub][0][j] + b2v[0]) * cce[j] * xv[msub][j][0];
                v1[j] = (c2[msub][1][j] + b2v[1]) * cce[j] * xv[msub][j][1];
            }
            const int fc0 = w * 32 + llo;
            const int fc1 = fc0 + 16;

            float h0 = v0[0], h1 = v1[0];
            if (!bB1) { h0 += v0[1]; h1 += v1[1];
                if (!bB2) { h0 += v0[2]; h1 += v1[2];
                    if (!bB3) { h0 += v0[3]; h1 += v1[3]; } } }
            float cs0 = v0[3], cs1 = v1[3];
            if (!bB3) { cs0 += v0[2]; cs1 += v1[2];
                if (!bB2) { cs0 += v0[1]; cs1 += v1[1];
                    if (!bB1) { cs0 += v0[0]; cs1 += v1[0]; } } }

            if (bB1 && bB2) { atomicAdd(&agg[rr[1] * H + fc0], v0[1]);
                              atomicAdd(&agg[rr[1] * H + fc1], v1[1]); }
            if (bB2 && bB3) { atomicAdd(&agg[rr[2] * H + fc0], v0[2]);
                              atomicAdd(&agg[rr[2] * H + fc1], v1[2]); }
            if (bB1 && !bB2 && bB3) {
                atomicAdd(&agg[rr[1] * H + fc0], v0[1] + v0[2]);
                atomicAdd(&agg[rr[1] * H + fc1], v1[1] + v1[2]);
            }

            bool f = !(sing && mrg);
            {
                float p0 = __shfl_up(cs0, 16), p1 = __shfl_up(cs1, 16);
                int   pf = __shfl_up((int)f, 16);
                if (lhi >= 1 && !f) { cs0 += p0; cs1 += p1; f = (bool)pf; }
            }
            {
                float p0 = __shfl_up(cs0, 32), p1 = __shfl_up(cs1, 32);
                int   pf = __shfl_up((int)f, 32);
                if (lhi >= 2 && !f) { cs0 += p0; cs1 += p1; f = (bool)pf; }
            }
            const float car0 = __shfl_up(cs0, 16);
            const float car1 = __shfl_up(cs1, 16);

            if (closed) {
                atomicAdd(&agg[rr[0] * H + fc0], h0 + (mrg ? car0 : 0.0f));
                atomicAdd(&agg[rr[0] * H + fc1], h1 + (mrg ? car1 : 0.0f));
            }
            if (issue_tail) {
                atomicAdd(&agg[rr[3] * H + fc0], cs0);
                atomicAdd(&agg[rr[3] * H + fc1], cs1);
            }
        }
    }
}

// ===== final: out = ssp(agg @ lin2_w + lin2_b) @ lin_w + lin_b (fp16 MFMA) =====
__global__ __launch_bounds__(256) void final_kernel(
    const float* __restrict__ agg,
    const float* __restrict__ w2l, const float* __restrict__ b2l,
    const float* __restrict__ wl,  const float* __restrict__ bl,
    float* __restrict__ out)
{
    __shared__ alignas(16) _Float16 a_lds[32 * H];
    __shared__ alignas(16) _Float16 t_lds[32 * H];

    const int tid = threadIdx.x;
    const int wv  = tid >> 6;
    const int l   = tid & 63;
    const int lhi = l >> 4;
    const int llo = l & 15;

    f16x8 b1f[2][4], b2f[2][4];
    #pragma unroll
    for (int nf = 0; nf < 2; ++nf) {
        const int n = wv * 32 + nf * 16 + llo;
        #pragma unroll
        for (int ks = 0; ks < 4; ++ks)
            #pragma unroll
            for (int i = 0; i < 8; ++i) {
                const int k = ks * 32 + lhi * 8 + i;
                b1f[nf][ks][i] = (_Float16)w2l[k * H + n];
                b2f[nf][ks][i] = (_Float16)wl[k * H + n];
            }
    }
    const float b2v[2] = { b2l[wv * 32 + llo], b2l[wv * 32 + 16 + llo] };
    const float bv[2]  = { bl[wv * 32 + llo],  bl[wv * 32 + 16 + llo]  };

    stage_tile_fp16(agg + (size_t)blockIdx.x * 32 * H, a_lds, tid);
    __syncthreads();

    f32x4 c1[2][2];
    #pragma unroll
    for (int m = 0; m < 2; ++m)
        #pragma unroll
        for (int nf = 0; nf < 2; ++nf) {
            c1[m][nf][0] = b2v[nf]; c1[m][nf][1] = b2v[nf];
            c1[m][nf][2] = b2v[nf]; c1[m][nf][3] = b2v[nf];
        }

    #pragma unroll
    for (int msub = 0; msub < 2; ++msub) {
        const int rowa = msub * 16 + llo;
        #pragma unroll
        for (int ks = 0; ks < 4; ++ks) {
            unsigned off = (unsigned)(rowa * H) * 2u + (unsigned)(ks * 64 + lhi * 16);
            off ^= (unsigned)((rowa & 7) << 4);
            const f16x8 a = *reinterpret_cast<const f16x8*>(
                reinterpret_cast<const char*>(a_lds) + off);
            #pragma unroll
            for (int nf = 0; nf < 2; ++nf)
                c1[msub][nf] = __builtin_amdgcn_mfma_f32_16x16x32_f16(
                    a, b1f[nf][ks], c1[msub][nf], 0, 0, 0);
        }
    }

    #pragma unroll
    for (int msub = 0; msub < 2; ++msub)
        #pragma unroll
        for (int nf = 0; nf < 2; ++nf)
            #pragma unroll
            for (int j = 0; j < 4; ++j) {
                const int rowc = msub * 16 + lhi * 4 + j;
                const int filt = wv * 32 + nf * 16 + llo;
                const float tv = ssp_fast(c1[msub][nf][j]);
                unsigned off = (unsigned)(rowc * H + filt) * 2u;
                off ^= (unsigned)((rowc & 7) << 4);
                *reinterpret_cast<_Float16*>(
                    reinterpret_cast<char*>(t_lds) + off) = (_Float16)tv;
            }

    __syncthreads();

    f32x4 c2[2][2];
    #pragma unroll
    for (int m = 0; m < 2; ++m)
        #pragma unroll
        for (int nf = 0; nf < 2; ++nf) {
            c2[m][nf][0] = bv[nf]; c2[m][nf][1] = bv[nf];
            c2[m][nf][2] = bv[nf]; c2[m][nf][3] = bv[nf];
        }

    #pragma unroll
    for (int msub = 0; msub < 2; ++msub) {
        const int rowa = msub * 16 + llo;
        #pragma unroll
        for (int ks = 0; ks < 4; ++ks) {
            unsigned off = (unsigned)(rowa * H) * 2u + (unsigned)(ks * 64 + lhi * 16);
            off ^= (unsigned)((rowa & 7) << 4);
            const f16x8 a = *reinterpret_cast<const f16x8*>(
                reinterpret_cast<const char*>(t_lds) + off);
            #pragma unroll
            for (int nf = 0; nf < 2; ++nf)
                c2[msub][nf] = __builtin_amdgcn_mfma_f32_16x16x32_f16(
                    a, b2f[nf][ks], c2[msub][nf], 0, 0, 0);
        }
    }

    #pragma unroll
    for (int msub = 0; msub < 2; ++msub)
        #pragma unroll
        for (int nf = 0; nf < 2; ++nf)
            #pragma unroll
            for (int j = 0; j < 4; ++j) {
                const int node = blockIdx.x * 32 + msub * 16 + lhi * 4 + j;
                const int filt = wv * 32 + nf * 16 + llo;
                out[(size_t)node * H + filt] = c2[msub][nf][j];
            }
}

extern "C" void kernel_launch(void* const* d_in, const int* in_sizes, int n_in,
                              void* d_out, int out_size, void* d_ws, size_t ws_size,
                              hipStream_t stream) {
    const float* h      = (const float*)d_in[0];
    const float* pos    = (const float*)d_in[1];
    const int*   ei     = (const int*)  d_in[2];
    const float* mlp_w1 = (const float*)d_in[3];
    const float* mlp_b1 = (const float*)d_in[4];
    const float* mlp_w2 = (const float*)d_in[5];
    const float* mlp_b2 = (const float*)d_in[6];
    const float* lin1_w = (const float*)d_in[7];
    const float* lin2_w = (const float*)d_in[8];
    const float* lin2_b = (const float*)d_in[9];
    const float* lin_w  = (const float*)d_in[10];
    const float* lin_b  = (const float*)d_in[11];

    float* out = (float*)d_out;
    char*  ws  = (char*)d_ws;
    float* agg  = (float*)ws;                               // 51.2 MB
    char*  p    = ws + (size_t)N_NODES * H * 4;
    int*   bins = (int*)p;                                  // 401 KB
    int*   bsum = (int*)(p + (size_t)NBINS * 4);            // 98 ints

    // d_out doubles as scratch until final_kernel overwrites it:
    __half* x    = (__half*)d_out;                          // 25.6 MB fp16 lin1 out
    int4*   meta = (int4*)((char*)d_out + (size_t)N_NODES * H * 2);  // 25.6 MB

    hipMemsetAsync(bins, 0, (size_t)NBINS * sizeof(int), stream);
    prep0_kernel<<<NODEB, 256, 0, stream>>>(ei, h, lin1_w, x, bins, agg);
    scanA_kernel<<<NBINS / 1024, 1024, 0, stream>>>(bins, bsum);
    scatter_kernel<<<(N_EDGES + 255) / 256, 256, 0, stream>>>(ei, pos, bins,
                                                              bsum, meta);
    edge_kernel<<<EBLK, 256, 0, stream>>>(meta, x, mlp_w1, mlp_b1,
                                          mlp_w2, mlp_b2, agg);
    final_kernel<<<NODEB, 256, 0, stream>>>(agg, lin2_w, lin2_b,
                                            lin_w, lin_b, out);
}